// Round 1
// baseline (1424.475 us; speedup 1.0000x reference)
//
#include <hip/hip_runtime.h>
#include <hip/hip_bf16.h>

// Fused masked-attention with materialized p_attn.
// B=2 H=8 N=4096 D=64, fp32 in/out. d_out = [out (B,H,N,D) | p_attn (B,H,N,N)].
//
// Design notes (round 1):
//  - Write-bound problem: p_attn = 1.074 GB fp32 writes. Roofline ~180us.
//  - One kernel, two passes per block: pass1 = rowsum of exp (QK^T recompute
//    is cheaper than spilling unnormalized p to HBM: +34 GF vs +2.1 GB).
//  - 512 blocks (2/CU), 512 thr (8 waves), wave owns 16 rows; BN=64 col tiles.
//  - mfma_f32_16x16x32_bf16; A/B frags = 8 contiguous bf16 along K from row
//    (lane&15), k-offset (lane>>4)*8; C/D: col=lane&15, row=(lane>>4)*4+reg.
//  - LDS row stride 72 bf16 (144B): even 8-lanes/bank distribution for all
//    b128 reads/writes (wave64 minimum, no conflict penalty).
//  - Masked row (mask[b,i]==0) -> p = 1/4096 uniform (matches jax softmax of
//    all -1e9); masked col -> p = 0 exactly.

typedef float f32x4 __attribute__((ext_vector_type(4)));
typedef short s16x8 __attribute__((ext_vector_type(8)));

#define MFMA16(a, b, c) __builtin_amdgcn_mfma_f32_16x16x32_bf16((a), (b), (c), 0, 0, 0)

__device__ __forceinline__ unsigned short f2bf(float f) {
    unsigned int u = __builtin_bit_cast(unsigned int, f);
    u += 0x7fffu + ((u >> 16) & 1u);   // RNE
    return (unsigned short)(u >> 16);
}

__device__ __forceinline__ s16x8 pack8(float4 a, float4 b) {
    s16x8 r;
    r[0] = (short)f2bf(a.x); r[1] = (short)f2bf(a.y);
    r[2] = (short)f2bf(a.z); r[3] = (short)f2bf(a.w);
    r[4] = (short)f2bf(b.x); r[5] = (short)f2bf(b.y);
    r[6] = (short)f2bf(b.z); r[7] = (short)f2bf(b.w);
    return r;
}

constexpr int   NN    = 4096;
constexpr int   DD    = 64;
constexpr float SCALE = 0.125f;          // 1/sqrt(64)
constexpr float UNIF  = 1.0f / 4096.0f;  // exact in bf16 (pow2)

__global__ __launch_bounds__(512, 4)
void attn_fused(const float* __restrict__ Qg, const float* __restrict__ Kg,
                const float* __restrict__ Vg, const int* __restrict__ Mg,
                float* __restrict__ Og, float* __restrict__ Pg)
{
    __shared__ unsigned short Kl[64 * 72];    // K tile, bf16, [kcol][d]
    __shared__ unsigned short Vt[64 * 72];    // V tile transposed, [d][j]
    __shared__ unsigned short Pl[128 * 72];   // p tile bf16, [row][j] (wave-private strips)
    __shared__ unsigned short Ml[NN];         // mask row for batch b

    const int t   = threadIdx.x;
    const int w   = t >> 6;     // wave 0..7
    const int l   = t & 63;
    const int l15 = l & 15;
    const int g   = l >> 4;     // 0..3

    const int bh = blockIdx.x >> 5;   // 16 (b,h), 32 row-blocks each (consecutive -> share K/V in L2)
    const int rb = blockIdx.x & 31;
    const int b  = bh >> 3;           // H = 8

    const size_t base = (size_t)bh * NN * DD;
    const float* Qb = Qg + base;
    const float* Kb = Kg + base;
    const float* Vb = Vg + base;

    // ---- stage mask row (4096 int32 -> u16 in LDS) ----
    {
        const int* mb = Mg + (size_t)b * NN;
        int4 m0 = ((const int4*)mb)[t * 2];
        int4 m1 = ((const int4*)mb)[t * 2 + 1];
        s16x8 mm;
        mm[0] = (short)m0.x; mm[1] = (short)m0.y; mm[2] = (short)m0.z; mm[3] = (short)m0.w;
        mm[4] = (short)m1.x; mm[5] = (short)m1.y; mm[6] = (short)m1.z; mm[7] = (short)m1.w;
        *(s16x8*)&Ml[t * 8] = mm;
    }

    const int row0 = rb * 128 + w * 16;    // wave's row-strip base (within this bh)

    // ---- preload Q A-fragments (both k-steps), straight from global ----
    s16x8 aq0, aq1;
    {
        const float* qp = Qb + (size_t)(row0 + l15) * DD + g * 8;
        aq0 = pack8(*(const float4*)qp, *(const float4*)(qp + 4));
        aq1 = pack8(*(const float4*)(qp + 32), *(const float4*)(qp + 36));
    }

    __syncthreads();   // mask staged

    int rmask[4];
    #pragma unroll
    for (int r = 0; r < 4; ++r) rmask[r] = (int)Ml[row0 + g * 4 + r];

    const int kr = t >> 3;          // K/V staging: row per 8-thread group
    const int kc = (t & 7) * 8;     // 8 floats per thread

    // ================= pass 1: rowsum of exp =================
    float rowsum[4] = {0.f, 0.f, 0.f, 0.f};
    for (int kt = 0; kt < 64; ++kt) {
        __syncthreads();
        {
            const float* kp = Kb + (size_t)(kt * 64 + kr) * DD + kc;
            *(s16x8*)&Kl[kr * 72 + kc] = pack8(*(const float4*)kp, *(const float4*)(kp + 4));
        }
        __syncthreads();
        #pragma unroll
        for (int t4 = 0; t4 < 4; ++t4) {
            s16x8 kb0 = *(const s16x8*)&Kl[(t4 * 16 + l15) * 72 + g * 8];
            s16x8 kb1 = *(const s16x8*)&Kl[(t4 * 16 + l15) * 72 + 32 + g * 8];
            f32x4 sa = {0.f, 0.f, 0.f, 0.f};
            sa = MFMA16(aq0, kb0, sa);
            sa = MFMA16(aq1, kb1, sa);
            const int cm = (int)Ml[kt * 64 + t4 * 16 + l15];
            #pragma unroll
            for (int r = 0; r < 4; ++r)
                rowsum[r] += cm ? __expf(sa[r] * SCALE) : 0.f;
        }
    }
    #pragma unroll
    for (int r = 0; r < 4; ++r) {
        float v = rowsum[r];
        v += __shfl_xor(v, 1); v += __shfl_xor(v, 2);
        v += __shfl_xor(v, 4); v += __shfl_xor(v, 8);
        rowsum[r] = v;
    }
    float inv[4];
    #pragma unroll
    for (int r = 0; r < 4; ++r) inv[r] = 1.0f / rowsum[r];  // masked rows: unused

    // ================= pass 2: p + out =================
    f32x4 o0 = {0,0,0,0}, o1 = {0,0,0,0}, o2 = {0,0,0,0}, o3 = {0,0,0,0};
    float* Pb = Pg + (size_t)bh * NN * NN;

    for (int kt = 0; kt < 64; ++kt) {
        __syncthreads();
        {   // stage K tile (bf16)
            const float* kp = Kb + (size_t)(kt * 64 + kr) * DD + kc;
            *(s16x8*)&Kl[kr * 72 + kc] = pack8(*(const float4*)kp, *(const float4*)(kp + 4));
        }
        {   // stage V tile transposed: wave w reads rows w*8..w*8+7, lane l = column l
            const float* vp = Vb + (size_t)(kt * 64 + w * 8) * DD + l;
            s16x8 vt;
            #pragma unroll
            for (int jj = 0; jj < 8; ++jj) vt[jj] = (short)f2bf(vp[jj * DD]);
            *(s16x8*)&Vt[l * 72 + w * 8] = vt;
        }
        __syncthreads();

        #pragma unroll
        for (int t4 = 0; t4 < 4; ++t4) {
            s16x8 kb0 = *(const s16x8*)&Kl[(t4 * 16 + l15) * 72 + g * 8];
            s16x8 kb1 = *(const s16x8*)&Kl[(t4 * 16 + l15) * 72 + 32 + g * 8];
            f32x4 sa = {0.f, 0.f, 0.f, 0.f};
            sa = MFMA16(aq0, kb0, sa);
            sa = MFMA16(aq1, kb1, sa);
            const int col = kt * 64 + t4 * 16 + l15;
            const int cm  = (int)Ml[col];
            #pragma unroll
            for (int r = 0; r < 4; ++r) {
                float p = (rmask[r] == 0) ? UNIF
                          : (cm ? __expf(sa[r] * SCALE) * inv[r] : 0.f);
                Pb[(size_t)(row0 + g * 4 + r) * NN + col] = p;                  // fp32 p_attn
                Pl[(w * 16 + g * 4 + r) * 72 + t4 * 16 + l15] = f2bf(p);        // bf16 for PV
            }
        }

        // PV: O[16x64] += P[16x64] * V[64x64]  (A from wave-private Pl strip)
        s16x8 ap0 = *(const s16x8*)&Pl[(w * 16 + l15) * 72 + g * 8];
        s16x8 ap1 = *(const s16x8*)&Pl[(w * 16 + l15) * 72 + 32 + g * 8];
        {
            s16x8 bv0, bv1;
            bv0 = *(const s16x8*)&Vt[(0  + l15) * 72 + g * 8];
            bv1 = *(const s16x8*)&Vt[(0  + l15) * 72 + 32 + g * 8];
            o0 = MFMA16(ap0, bv0, o0); o0 = MFMA16(ap1, bv1, o0);
            bv0 = *(const s16x8*)&Vt[(16 + l15) * 72 + g * 8];
            bv1 = *(const s16x8*)&Vt[(16 + l15) * 72 + 32 + g * 8];
            o1 = MFMA16(ap0, bv0, o1); o1 = MFMA16(ap1, bv1, o1);
            bv0 = *(const s16x8*)&Vt[(32 + l15) * 72 + g * 8];
            bv1 = *(const s16x8*)&Vt[(32 + l15) * 72 + 32 + g * 8];
            o2 = MFMA16(ap0, bv0, o2); o2 = MFMA16(ap1, bv1, o2);
            bv0 = *(const s16x8*)&Vt[(48 + l15) * 72 + g * 8];
            bv1 = *(const s16x8*)&Vt[(48 + l15) * 72 + 32 + g * 8];
            o3 = MFMA16(ap0, bv0, o3); o3 = MFMA16(ap1, bv1, o3);
        }
    }

    // ---- epilogue: write O ----
    float* ob = Og + ((size_t)bh * NN + row0) * DD;
    #pragma unroll
    for (int r = 0; r < 4; ++r) {
        const size_t ro = (size_t)(g * 4 + r) * DD + l15;
        ob[ro]      = o0[r];
        ob[ro + 16] = o1[r];
        ob[ro + 32] = o2[r];
        ob[ro + 48] = o3[r];
    }
}

extern "C" void kernel_launch(void* const* d_in, const int* in_sizes, int n_in,
                              void* d_out, int out_size, void* d_ws, size_t ws_size,
                              hipStream_t stream)
{
    const float* Q = (const float*)d_in[0];
    const float* K = (const float*)d_in[1];
    const float* V = (const float*)d_in[2];
    const int*   M = (const int*)d_in[3];

    float* out = (float*)d_out;
    float* p   = out + (size_t)2 * 8 * 4096 * 64;   // p_attn after out

    attn_fused<<<512, 512, 0, stream>>>(Q, K, V, M, out, p);
}